// Round 4
// baseline (9.630 us; speedup 1.0000x reference)
//
#include <hip/hip_runtime.h>
#include <math.h>

// Problem constants from the reference
#define BB 16
#define TT 100
#define VV 50000
#define SS 4
#define NPAIRS (BB * TT)            // 1600
#define NBLK ((NPAIRS + 63) / 64)   // 25 blocks, 1 wave each
#define MAGIC 0x5F3C9A1Bu

// Single fused kernel. Each of 25 blocks wave-reduces its 64 (b,t) pairs and
// release-publishes {MAGIC|payload} as ONE 64-bit slot (flag and data travel
// together -> single acquire round for the reader). Block 0 spins, sums in
// fixed lane order (bitwise deterministic), writes the scalar.
__global__ __launch_bounds__(64)
void bpr_fused_kernel(const float* __restrict__ output,
                      const int*   __restrict__ labels,
                      const int*   __restrict__ x_lens,
                      const int*   __restrict__ neg_ids,
                      unsigned long long* __restrict__ slots,  // ws: NBLK packed slots
                      float*       __restrict__ out) {
    const int lane = threadIdx.x;
    const int blk  = blockIdx.x;
    const int i    = blk * 64 + lane;

    float acc = 0.0f;
    if (i < NPAIRS) {
        // Independent index loads issue together (one latency round).
        const int  lab = labels[i];
        const int4 nid = *((const int4*)neg_ids + i);   // SS=4 ints, 16B aligned
        const int  b   = i / TT;
        const int  t   = i - b * TT;
        const int  xl  = x_lens[b];

        if (t < xl) {
            const float* row = output + (size_t)i * VV;  // output[b, t, :]
            // One gather round: pos + 4 negs in flight simultaneously.
            const float pos = row[lab];
            const float n0  = row[nid.x];
            const float n1  = row[nid.y];
            const float n2  = row[nid.z];
            const float n3  = row[nid.w];

            float s = 0.0f;
            const float xs[4] = {pos - n0, pos - n1, pos - n2, pos - n3};
            #pragma unroll
            for (int s_i = 0; s_i < SS; ++s_i) {
                const float x = xs[s_i];
                // log_sigmoid(x) = min(x,0) - log1p(exp(-|x|))  (stable)
                s += fminf(x, 0.0f) - log1pf(__expf(-fabsf(x)));
            }
            acc = s / (float)xl;
        }
    }

    // Deterministic wave-64 shuffle reduction; block partial lands in lane 0.
    #pragma unroll
    for (int off = 32; off > 0; off >>= 1)
        acc += __shfl_down(acc, off, 64);

    // Publish: payload and flag in one 64-bit release store (block 0 keeps
    // its own partial in-register, no round trip needed).
    if (lane == 0 && blk != 0) {
        const unsigned long long packed =
            ((unsigned long long)MAGIC << 32) | (unsigned long long)__float_as_uint(acc);
        __hip_atomic_store(&slots[blk], packed, __ATOMIC_RELEASE, __HIP_MEMORY_SCOPE_AGENT);
    }

    if (blk == 0) {
        float v = 0.0f;
        if (lane == 0) {
            v = acc;                          // own partial, no global trip
        } else if (lane < NBLK) {
            unsigned long long p;
            do {                              // single acquire round: flag+data together
                p = __hip_atomic_load(&slots[lane], __ATOMIC_ACQUIRE,
                                      __HIP_MEMORY_SCOPE_AGENT);
            } while ((unsigned)(p >> 32) != MAGIC);
            v = __uint_as_float((unsigned)p);
        }
        // Live values only in lanes 0..24 -> offs 16,8,4,2,1 suffice (lanes
        // 25..63 carry zeros and never fold in past off=16).
        #pragma unroll
        for (int off = 16; off > 0; off >>= 1)
            v += __shfl_down(v, off, 64);
        if (lane == 0)
            out[0] = -v / (float)BB;
    }
}

extern "C" void kernel_launch(void* const* d_in, const int* in_sizes, int n_in,
                              void* d_out, int out_size, void* d_ws, size_t ws_size,
                              hipStream_t stream) {
    // setup_inputs() order: output, labels, x_lens, uids, neg_ids
    const float* output  = (const float*)d_in[0];
    const int*   labels  = (const int*)  d_in[1];
    const int*   x_lens  = (const int*)  d_in[2];
    // d_in[3] = uids (unused by the reference math)
    const int*   neg_ids = (const int*)  d_in[4];
    float*       out     = (float*)d_out;

    unsigned long long* slots = (unsigned long long*)d_ws;   // NBLK packed slots

    bpr_fused_kernel<<<NBLK, 64, 0, stream>>>(output, labels, x_lens, neg_ids,
                                              slots, out);
}